// Round 12
// baseline (283.042 us; speedup 1.0000x reference)
//
#include <hip/hip_runtime.h>
#include <math.h>
#include <stdint.h>

// Problem constants (fixed by setup_inputs: B=8, h=w=64, C=256)
#define TT 4096
#define HH 64
#define WW 64
#define CC 256
#define NCH 64
#define LCH 64

typedef __bf16 bf16x8 __attribute__((ext_vector_type(8)));
typedef float  f32x4  __attribute__((ext_vector_type(4)));

__device__ __forceinline__ unsigned short f2bf(float x) {
    uint32_t u = __float_as_uint(x);
    u = (u + 0x7fffu + ((u >> 16) & 1u)) >> 16;
    return (unsigned short)u;
}
__device__ __forceinline__ float bf2f(unsigned short h) {
    return __uint_as_float(((uint32_t)h) << 16);
}
__device__ __forceinline__ float fast_rcp(float x) {
    float r;
    asm("v_rcp_f32 %0, %1" : "=v"(r) : "v"(x));
    return r;
}

// ---------------------------------------------------------------------------
// Fused prep: blocks [0,25) build weff; [25,281) split Wk/Wv/Wr rows;
// [281,537) split Wo rows. One launch instead of three.
__global__ __launch_bounds__(256)
void prep_all(const float* __restrict__ alpha,
              const float* __restrict__ cw1,
              const float* __restrict__ cw3,
              const float* __restrict__ cw5,
              const float* __restrict__ Wk, const float* __restrict__ Wv,
              const float* __restrict__ Wr, const float* __restrict__ Wo,
              float* __restrict__ weff,
              unsigned short* __restrict__ W2k, unsigned short* __restrict__ W2v,
              unsigned short* __restrict__ W2r, unsigned short* __restrict__ Wo2,
              int do_wo) {
    int bid = blockIdx.x, c = threadIdx.x;
    if (bid < 25) {
        int k = bid;
        float a0 = alpha[0], a1 = alpha[1], a2 = alpha[2], a3 = alpha[3];
        float v = a3 * cw5[c * 25 + k];
        int ky = k / 5, kx = k % 5;
        if (ky >= 1 && ky <= 3 && kx >= 1 && kx <= 3)
            v += a2 * cw3[c * 9 + (ky - 1) * 3 + (kx - 1)];
        if (k == 12) v += a1 * cw1[c] + a0;
        weff[k * CC + c] = v;
    } else if (bid < 281) {
        int n = bid - 25;
        float a;
        unsigned short h;
        a = Wk[n * 256 + c]; h = f2bf(a); W2k[n * 512 + c] = h; W2k[n * 512 + 256 + c] = f2bf(a - bf2f(h));
        a = Wv[n * 256 + c]; h = f2bf(a); W2v[n * 512 + c] = h; W2v[n * 512 + 256 + c] = f2bf(a - bf2f(h));
        a = Wr[n * 256 + c]; h = f2bf(a); W2r[n * 512 + c] = h; W2r[n * 512 + 256 + c] = f2bf(a - bf2f(h));
    } else if (do_wo) {
        int n = bid - 281;
        float a = Wo[n * 512 + c];
        unsigned short h = f2bf(a);
        Wo2[n * 1024 + c] = h; Wo2[n * 1024 + 256 + c] = f2bf(a - bf2f(h));
        float b = Wo[n * 512 + 256 + c];
        unsigned short h2 = f2bf(b);
        Wo2[n * 1024 + 512 + c] = h2; Wo2[n * 1024 + 768 + c] = f2bf(b - bf2f(h2));
    }
}

// Fallback late Wo split (only used when ws lacks the dedicated slot).
__global__ __launch_bounds__(256)
void prep_wo(const float* __restrict__ Wo, unsigned short* __restrict__ Wo2) {
    int n = blockIdx.x, c = threadIdx.x;
    float a = Wo[n * 512 + c];
    unsigned short h = f2bf(a);
    Wo2[n * 1024 + c] = h; Wo2[n * 1024 + 256 + c] = f2bf(a - bf2f(h));
    float b = Wo[n * 512 + 256 + c];
    unsigned short h2 = f2bf(b);
    Wo2[n * 1024 + 512 + c] = h2; Wo2[n * 1024 + 768 + c] = f2bf(b - bf2f(h2));
}

// ---------------------------------------------------------------------------
// Depthwise 5x5 conv, sliding-window over y. Block = (x-column, y-strip, b),
// thread = channel. Output split to [hi | lo] bf16 (row stride 512).
__global__ __launch_bounds__(256)
void omni_conv(const float* __restrict__ x,
               const float* __restrict__ weff,
               unsigned short* __restrict__ A2) {
    int xx = blockIdx.x;          // 0..63
    int y0 = blockIdx.y * 32;     // strip start
    int b  = blockIdx.z;
    int c  = threadIdx.x;
    const float* xb = x + (size_t)b * TT * CC + c;
    unsigned short* Ab = A2 + (size_t)b * TT * 512 + c;

    float wk[25];
    #pragma unroll
    for (int k = 0; k < 25; ++k) wk[k] = weff[k * CC + c];

    float win[5][5];  // [row][dx], row i = y-2+i
    #pragma unroll
    for (int i = 0; i < 4; ++i) {
        int yy = y0 - 2 + i;
        #pragma unroll
        for (int dx = 0; dx < 5; ++dx) {
            int xc = xx + dx - 2;
            win[i][dx] = (yy >= 0 && xc >= 0 && xc < WW)
                         ? xb[(size_t)(yy * WW + xc) * CC] : 0.f;
        }
    }
    #pragma unroll
    for (int i = 0; i < 32; ++i) {
        int y = y0 + i;
        int yy = y + 2;
        #pragma unroll
        for (int dx = 0; dx < 5; ++dx) {
            int xc = xx + dx - 2;
            win[4][dx] = (yy < HH && xc >= 0 && xc < WW)
                         ? xb[(size_t)(yy * WW + xc) * CC] : 0.f;
        }
        float acc = 0.f;
        #pragma unroll
        for (int r = 0; r < 5; ++r)
            #pragma unroll
            for (int dx = 0; dx < 5; ++dx)
                acc = fmaf(wk[r * 5 + dx], win[r][dx], acc);
        unsigned short h = f2bf(acc);
        size_t o = (size_t)(y * WW + xx) * 512;
        Ab[o] = h;
        Ab[o + 256] = f2bf(acc - bf2f(h));
        #pragma unroll
        for (int r = 0; r < 4; ++r)
            #pragma unroll
            for (int dx = 0; dx < 5; ++dx)
                win[r][dx] = win[r + 1][dx];
    }
}

// ---------------------------------------------------------------------------
// bf16x3 MFMA GEMM (NT), chunked staging + T4 counted-vmcnt pipeline
// (frozen since round 9 for attribution).
template<int KIND>   // 0: kvr (K=256, 8 chunks). 1: out (K=512, 16 chunks)
__device__ __forceinline__ void mfma_core(const unsigned short* __restrict__ A0,
                                          const unsigned short* __restrict__ A1,
                                          const unsigned short* __restrict__ W2,
                                          float* __restrict__ C,
                                          int m_blk, int n_blk, bool act) {
    // [buf][tile][128 rows x 32 cols] ; tiles: 0=Ah 1=Al 2=Wh 3=Wl
    __shared__ __align__(16) unsigned short L[2][4][128 * 32];
    int tid = threadIdx.x;
    int w = tid >> 6, l = tid & 63;
    int q = l >> 4, rr = l & 15;           // mfma frag coords
    int wm = (w & 1) * 64, wn = (w >> 1) * 64;
    int srw = w * 16 + (l >> 2);           // stage: row within 64-row half
    int ss  = l & 3;                       // stage: 16B slot

    const int NCHK = (KIND == 0) ? 8 : 16;
    const int LDW  = (KIND == 0) ? 512 : 1024;

    f32x4 acc[4][4];
    #pragma unroll
    for (int i = 0; i < 4; ++i)
        #pragma unroll
        for (int j = 0; j < 4; ++j)
            acc[i][j] = (f32x4){0.f, 0.f, 0.f, 0.f};

    auto stage = [&](int cc, int buf) {
        const unsigned short* Ab;
        int ah, al, wh, wl;
        if (KIND == 0) {
            Ab = A0; ah = cc * 32; al = 256 + cc * 32;
            wh = cc * 32; wl = 256 + cc * 32;
        } else {
            int c8 = cc & 7;
            Ab = (cc < 8) ? A0 : A1;
            ah = c8 * 32; al = 256 + c8 * 32;
            wh = ((cc < 8) ? 0 : 512) + c8 * 32;
            wl = ((cc < 8) ? 256 : 768) + c8 * 32;
        }
        #pragma unroll
        for (int i = 0; i < 2; ++i) {
            int r = i * 64 + srw;                       // row in 128-tile
            int sl = (ss ^ ((r >> 1) & 3)) * 8;         // pre-swizzled src slot
            size_t arow = (size_t)(m_blk + r) * 512;
            size_t wrow = (size_t)(n_blk + r) * LDW;
            int db = (i * 64 + w * 16) * 32;            // linear LDS dest (ushorts)
            __builtin_amdgcn_global_load_lds(
                (const __attribute__((address_space(1))) void*)(Ab + arow + ah + sl),
                (__attribute__((address_space(3))) void*)&L[buf][0][db], 16, 0, 0);
            __builtin_amdgcn_global_load_lds(
                (const __attribute__((address_space(1))) void*)(Ab + arow + al + sl),
                (__attribute__((address_space(3))) void*)&L[buf][1][db], 16, 0, 0);
            __builtin_amdgcn_global_load_lds(
                (const __attribute__((address_space(1))) void*)(W2 + wrow + wh + sl),
                (__attribute__((address_space(3))) void*)&L[buf][2][db], 16, 0, 0);
            __builtin_amdgcn_global_load_lds(
                (const __attribute__((address_space(1))) void*)(W2 + wrow + wl + sl),
                (__attribute__((address_space(3))) void*)&L[buf][3][db], 16, 0, 0);
        }
    };

    stage(0, 0);
    stage(1, 1);

    for (int cc = 0; cc < NCHK; ++cc) {
        int buf = cc & 1;
        if (cc + 1 < NCHK) {
            asm volatile("s_waitcnt vmcnt(8)" ::: "memory");
        } else {
            asm volatile("s_waitcnt vmcnt(0)" ::: "memory");
        }
        __builtin_amdgcn_s_barrier();

        bf16x8 ah4[4], al4[4], wh4[4], wl4[4];
        #pragma unroll
        for (int f = 0; f < 4; ++f) {
            int Ra = wm + f * 16 + rr;
            int sa = (q ^ ((Ra >> 1) & 3)) * 8;
            ah4[f] = *(const bf16x8*)&L[buf][0][Ra * 32 + sa];
            al4[f] = *(const bf16x8*)&L[buf][1][Ra * 32 + sa];
            int Rw = wn + f * 16 + rr;
            int sw2 = (q ^ ((Rw >> 1) & 3)) * 8;
            wh4[f] = *(const bf16x8*)&L[buf][2][Rw * 32 + sw2];
            wl4[f] = *(const bf16x8*)&L[buf][3][Rw * 32 + sw2];
        }
        __builtin_amdgcn_s_setprio(1);
        #pragma unroll
        for (int fm = 0; fm < 4; ++fm)
            #pragma unroll
            for (int fn = 0; fn < 4; ++fn)
                acc[fm][fn] = __builtin_amdgcn_mfma_f32_16x16x32_bf16(
                    ah4[fm], wh4[fn], acc[fm][fn], 0, 0, 0);
        #pragma unroll
        for (int fm = 0; fm < 4; ++fm)
            #pragma unroll
            for (int fn = 0; fn < 4; ++fn)
                acc[fm][fn] = __builtin_amdgcn_mfma_f32_16x16x32_bf16(
                    al4[fm], wh4[fn], acc[fm][fn], 0, 0, 0);
        #pragma unroll
        for (int fm = 0; fm < 4; ++fm)
            #pragma unroll
            for (int fn = 0; fn < 4; ++fn)
                acc[fm][fn] = __builtin_amdgcn_mfma_f32_16x16x32_bf16(
                    ah4[fm], wl4[fn], acc[fm][fn], 0, 0, 0);
        __builtin_amdgcn_s_setprio(0);

        __builtin_amdgcn_s_barrier();     // all waves done reading buf
        if (cc + 2 < NCHK) stage(cc + 2, buf);
    }

    // Epilogue: C/D layout col=lane&15, row=(lane>>4)*4+reg (m89-verified).
    #pragma unroll
    for (int fm = 0; fm < 4; ++fm)
        #pragma unroll
        for (int fn = 0; fn < 4; ++fn) {
            int col = n_blk + wn + fn * 16 + rr;
            int row0 = m_blk + wm + fm * 16 + q * 4;
            f32x4 v = acc[fm][fn];
            #pragma unroll
            for (int j = 0; j < 4; ++j) {
                float o = v[j];
                if (act) o = 1.f / (1.f + __expf(-o));
                C[(size_t)(row0 + j) * 256 + col] = o;
            }
        }
}

// XCD-bijective decode: id = xcd + 8*(v + NV*mq) -> all NV variants of m-block
// (mq*8 + xcd) land on the same XCD. (M/128) % 8 == 0 always (M/128 = B*32).
__global__ __launch_bounds__(256, 2)
void gemm_kvr_mfma(const unsigned short* __restrict__ A2,
                   const unsigned short* __restrict__ W2k,
                   const unsigned short* __restrict__ W2v,
                   const unsigned short* __restrict__ W2r,
                   float* __restrict__ kb, float* __restrict__ vb,
                   float* __restrict__ rb) {
    int id = blockIdx.x;
    int xcd = id & 7;
    int j = id >> 3;
    int v = j % 6;
    int mq = j / 6;
    int m_blk = (mq * 8 + xcd) * 128;
    int mat = v >> 1;
    int n_blk = (v & 1) * 128;
    const unsigned short* W2 = (mat == 0) ? W2k : (mat == 1) ? W2v : W2r;
    float* C = (mat == 0) ? kb : (mat == 1) ? vb : rb;
    mfma_core<0>(A2, A2, W2, C, m_blk, n_blk, mat == 2);
}

__global__ __launch_bounds__(256, 2)
void gemm_out_mfma(const unsigned short* __restrict__ xs0,
                   const unsigned short* __restrict__ xs1,
                   const unsigned short* __restrict__ Wo2,
                   float* __restrict__ out) {
    int id = blockIdx.x;
    int xcd = id & 7;
    int j = id >> 3;
    int v = j & 1;
    int mq = j >> 1;
    int m_blk = (mq * 8 + xcd) * 128;
    mfma_core<1>(xs0, xs1, Wo2, out, m_blk, v * 128, false);
}

// ---------------------------------------------------------------------------
// Chunk-parallel WKV (state (a,b,p) = unnormalized (a*e^p, b*e^p)).
// Pass 1: local chunk states; 2 chunks (ch, ch+32) per thread for ILP.
__global__ __launch_bounds__(256)
void wkv_pass1(const float* __restrict__ kin, const float* __restrict__ vin,
               const float* __restrict__ sdecay,
               float* __restrict__ cs_a, float* __restrict__ cs_b,
               float* __restrict__ cs_p) {
    int chA = blockIdx.x, dir = blockIdx.y, bb = blockIdx.z, c = threadIdx.x;
    int chB = chA + NCH / 2;
    float wd = -expf(sdecay[dir * CC + c] * (1.f / TT));
    const float* kb = kin + (size_t)bb * TT * CC + c;
    const float* vb = vin + (size_t)bb * TT * CC + c;
    float aA = 0.f, bA = 0.f, pA = -1e38f;
    float aB = 0.f, bB = 0.f, pB = -1e38f;
    for (int i0 = 0; i0 < LCH; i0 += 8) {
        float kA8[8], vA8[8], kB8[8], vB8[8];
        #pragma unroll
        for (int i = 0; i < 8; ++i) {
            int ii = i0 + i;
            int sA = dir ? (ii * WW + chA) : (chA * LCH + ii);
            int sB = dir ? (ii * WW + chB) : (chB * LCH + ii);
            kA8[i] = kb[(size_t)sA * CC]; vA8[i] = vb[(size_t)sA * CC];
            kB8[i] = kb[(size_t)sB * CC]; vB8[i] = vb[(size_t)sB * CC];
        }
        #pragma unroll
        for (int i = 0; i < 8; ++i) {
            {
                float kt = kA8[i], vt = vA8[i];
                float ww2 = pA + wd;
                float p2 = fmaxf(ww2, kt);
                float f1 = __expf(ww2 - p2), f2 = __expf(kt - p2);
                aA = f1 * aA + f2 * vt; bA = f1 * bA + f2; pA = p2;
            }
            {
                float kt = kB8[i], vt = vB8[i];
                float ww2 = pB + wd;
                float p2 = fmaxf(ww2, kt);
                float f1 = __expf(ww2 - p2), f2 = __expf(kt - p2);
                aB = f1 * aB + f2 * vt; bB = f1 * bB + f2; pB = p2;
            }
        }
    }
    size_t base = (size_t)(bb * 2 + dir) * NCH * CC + c;
    size_t oA = base + (size_t)chA * CC, oB = base + (size_t)chB * CC;
    cs_a[oA] = aA; cs_b[oA] = bA; cs_p[oA] = pA;
    cs_a[oB] = aB; cs_b[oB] = bB; cs_p[oB] = pB;
}

// Parallel chunk-prefix: one wave per (channel, dir, b); chunk index on lanes.
// Kogge-Stone with span-decay D = Ld*2^s (valid: step-s partner spans exactly
// 2^s chunks). Writes EXCLUSIVE prefix (entry states) back over cs in-place.
__global__ __launch_bounds__(64)
void wkv_scan2(const float* __restrict__ sdecay,
               float* __restrict__ cs_a, float* __restrict__ cs_b,
               float* __restrict__ cs_p) {
    int c = blockIdx.x, dir = blockIdx.y, bb = blockIdx.z;
    int lane = threadIdx.x;   // chunk
    float wd = -expf(sdecay[dir * CC + c] * (1.f / TT));
    float Ld = (float)LCH * wd;
    size_t o = (size_t)(bb * 2 + dir) * NCH * CC + (size_t)lane * CC + c;
    float a = cs_a[o], b = cs_b[o], p = cs_p[o];
    #pragma unroll
    for (int s = 0; s < 6; ++s) {
        int dlt = 1 << s;
        float xa = __shfl_up(a, dlt, 64);
        float xb = __shfl_up(b, dlt, 64);
        float xp = __shfl_up(p, dlt, 64);
        if (lane >= dlt) {
            float sh = xp + Ld * (float)dlt;
            float pn = fmaxf(sh, p);
            float e1 = __expf(sh - pn), e2 = __expf(p - pn);
            a = e1 * xa + e2 * a; b = e1 * xb + e2 * b; p = pn;
        }
    }
    // exclusive shift: entry[ch] = inclusive[ch-1]; entry[0] = identity
    float ea = __shfl_up(a, 1, 64);
    float eb = __shfl_up(b, 1, 64);
    float ep = __shfl_up(p, 1, 64);
    if (lane == 0) { ea = 0.f; eb = 0.f; ep = -1e38f; }
    cs_a[o] = ea; cs_b[o] = eb; cs_p[o] = ep;
}

// Pass 3: load entry state, emit (out*sr) split to hi/lo bf16.
// 2 chunks (ch, ch+32) per thread for ILP; v_rcp_f32 for the divide.
__global__ __launch_bounds__(256)
void wkv_pass3(const float* __restrict__ kin, const float* __restrict__ vin,
               const float* __restrict__ srin,
               const float* __restrict__ sdecay, const float* __restrict__ sfirst,
               const float* __restrict__ cs_a, const float* __restrict__ cs_b,
               const float* __restrict__ cs_p,
               unsigned short* __restrict__ xs2_0, unsigned short* __restrict__ xs2_1) {
    int chA = blockIdx.x, dir = blockIdx.y, bb = blockIdx.z, c = threadIdx.x;
    int chB = chA + NCH / 2;
    int d = dir * CC + c;
    float u  = sfirst[d] * (1.f / TT);
    float wd = -expf(sdecay[d] * (1.f / TT));
    size_t base = (size_t)(bb * 2 + dir) * NCH * CC + c;
    size_t oA = base + (size_t)chA * CC, oB = base + (size_t)chB * CC;
    float aA = cs_a[oA], bA = cs_b[oA], pA = cs_p[oA];
    float aB = cs_a[oB], bB = cs_b[oB], pB = cs_p[oB];
    const float* kb  = kin  + (size_t)bb * TT * CC + c;
    const float* vb  = vin  + (size_t)bb * TT * CC + c;
    const float* srb = srin + (size_t)bb * TT * CC + c;
    unsigned short* xo = (dir ? xs2_1 : xs2_0) + (size_t)bb * TT * 512 + c;
    for (int i0 = 0; i0 < LCH; i0 += 8) {
        float kA8[8], vA8[8], sA8[8], kB8[8], vB8[8], sB8[8];
        #pragma unroll
        for (int i = 0; i < 8; ++i) {
            int ii = i0 + i;
            int tA = chA * LCH + ii;
            int tB = chB * LCH + ii;
            int sA = dir ? (ii * WW + chA) : tA;
            int sB = dir ? (ii * WW + chB) : tB;
            kA8[i] = kb[(size_t)sA * CC]; vA8[i] = vb[(size_t)sA * CC];
            sA8[i] = srb[(size_t)tA * CC];
            kB8[i] = kb[(size_t)sB * CC]; vB8[i] = vb[(size_t)sB * CC];
            sB8[i] = srb[(size_t)tB * CC];
        }
        #pragma unroll
        for (int i = 0; i < 8; ++i) {
            {
                int t = chA * LCH + i0 + i;
                float kt = kA8[i], vt = vA8[i];
                float ww = u + kt;
                float qq = fmaxf(pA, ww);
                float e1 = __expf(pA - qq), e2 = __expf(ww - qq);
                float num = e1 * aA + e2 * vt;
                float den = e1 * bA + e2;
                float os = num * fast_rcp(den) * sA8[i];
                unsigned short h = f2bf(os);
                xo[(size_t)t * 512] = h;
                xo[(size_t)t * 512 + 256] = f2bf(os - bf2f(h));
                float ww2 = pA + wd;
                float p2  = fmaxf(ww2, kt);
                float f1 = __expf(ww2 - p2), f2 = __expf(kt - p2);
                aA = f1 * aA + f2 * vt; bA = f1 * bA + f2; pA = p2;
            }
            {
                int t = chB * LCH + i0 + i;
                float kt = kB8[i], vt = vB8[i];
                float ww = u + kt;
                float qq = fmaxf(pB, ww);
                float e1 = __expf(pB - qq), e2 = __expf(ww - qq);
                float num = e1 * aB + e2 * vt;
                float den = e1 * bB + e2;
                float os = num * fast_rcp(den) * sB8[i];
                unsigned short h = f2bf(os);
                xo[(size_t)t * 512] = h;
                xo[(size_t)t * 512 + 256] = f2bf(os - bf2f(h));
                float ww2 = pB + wd;
                float p2  = fmaxf(ww2, kt);
                float f1 = __expf(ww2 - p2), f2 = __expf(kt - p2);
                aB = f1 * aB + f2 * vt; bB = f1 * bB + f2; pB = p2;
            }
        }
    }
}

// ---------------------------------------------------------------------------
extern "C" void kernel_launch(void* const* d_in, const int* in_sizes, int n_in,
                              void* d_out, int out_size, void* d_ws, size_t ws_size,
                              hipStream_t stream) {
    const float* x     = (const float*)d_in[0];
    const float* alpha = (const float*)d_in[1];
    const float* cw1   = (const float*)d_in[2];
    const float* cw3   = (const float*)d_in[3];
    const float* cw5   = (const float*)d_in[4];
    const float* Wk    = (const float*)d_in[5];
    const float* Wv    = (const float*)d_in[6];
    const float* Wr    = (const float*)d_in[7];
    const float* Wo    = (const float*)d_in[8];
    const float* sd    = (const float*)d_in[9];
    const float* sf    = (const float*)d_in[10];
    (void)n_in; (void)out_size;

    int B = in_sizes[0] / (TT * CC);
    int M = B * TT;
    size_t S = (size_t)M * 1024;  // bytes per slot

    char* wsb = (char*)d_ws;
    unsigned short* A2    = (unsigned short*)wsb;        // slot0; later xs2_0
    float*          kbuf  = (float*)(wsb + 1 * S);
    float*          vbuf  = (float*)(wsb + 2 * S);
    float*          srbuf = (float*)(wsb + 3 * S);
    unsigned short* xs2_1 = (unsigned short*)(wsb + 4 * S);
    unsigned short* xs2_0 = A2;

    // Wo2: dedicated slot after slot 4 if ws has room (early prep, fused
    // launch); else overlay srbuf and split late (fallback path).
    bool wo_early = (ws_size >= 5 * S + 524288);
    unsigned short* Wo2 = wo_early ? (unsigned short*)(wsb + 5 * S)
                                   : (unsigned short*)(wsb + 3 * S);

    // d_out as scratch until gemm_out overwrites it entirely.
    size_t SC = (size_t)B * 2 * NCH * CC;
    char* ob = (char*)d_out;
    float* cs_a = (float*)ob;
    float* cs_b = (float*)(ob + SC * 4);
    float* cs_p = (float*)(ob + 2 * SC * 4);
    float* weff = (float*)(ob + 3 * SC * 4);
    unsigned short* W2k = (unsigned short*)(ob + (4u << 20));
    unsigned short* W2v = (unsigned short*)(ob + (4u << 20) + 262144);
    unsigned short* W2r = (unsigned short*)(ob + (4u << 20) + 524288);

    prep_all<<<537, CC, 0, stream>>>(alpha, cw1, cw3, cw5, Wk, Wv, Wr, Wo,
                                     weff, W2k, W2v, W2r, Wo2,
                                     wo_early ? 1 : 0);
    omni_conv<<<dim3(WW, 2, B), CC, 0, stream>>>(x, weff, A2);

    gemm_kvr_mfma<<<(M / 128) * 6, 256, 0, stream>>>(A2, W2k, W2v, W2r,
                                                     kbuf, vbuf, srbuf);

    wkv_pass1<<<dim3(NCH / 2, 2, B), 256, 0, stream>>>(kbuf, vbuf, sd,
                                                       cs_a, cs_b, cs_p);
    wkv_scan2<<<dim3(CC, 2, B), 64, 0, stream>>>(sd, cs_a, cs_b, cs_p);
    wkv_pass3<<<dim3(NCH / 2, 2, B), 256, 0, stream>>>(kbuf, vbuf, srbuf, sd, sf,
                                                       cs_a, cs_b, cs_p,
                                                       xs2_0, xs2_1);

    if (!wo_early)
        prep_wo<<<256, CC, 0, stream>>>(Wo, Wo2);
    gemm_out_mfma<<<(M / 128) * 2, 256, 0, stream>>>(xs2_0, xs2_1, Wo2,
                                                     (float*)d_out);
}

// Round 13
// 243.308 us; speedup vs baseline: 1.1633x; 1.1633x over previous
//
#include <hip/hip_runtime.h>
#include <math.h>
#include <stdint.h>

// Problem constants (fixed by setup_inputs: B=8, h=w=64, C=256)
#define TT 4096
#define HH 64
#define WW 64
#define CC 256
#define NCH 64
#define LCH 64

typedef __bf16 bf16x8 __attribute__((ext_vector_type(8)));
typedef float  f32x4  __attribute__((ext_vector_type(4)));

__device__ __forceinline__ unsigned short f2bf(float x) {
    uint32_t u = __float_as_uint(x);
    u = (u + 0x7fffu + ((u >> 16) & 1u)) >> 16;
    return (unsigned short)u;
}
__device__ __forceinline__ float bf2f(unsigned short h) {
    return __uint_as_float(((uint32_t)h) << 16);
}
__device__ __forceinline__ float fast_rcp(float x) {
    float r;
    asm("v_rcp_f32 %0, %1" : "=v"(r) : "v"(x));
    return r;
}

// ---------------------------------------------------------------------------
// Fused prep: [0,25) weff; [25,281) split Wk/Wv/Wr ([hi|lo] 512/row);
// [281,537) split Wo ([hi 512 | lo 512] per row, LDW=1024).
__global__ __launch_bounds__(256)
void prep_all(const float* __restrict__ alpha,
              const float* __restrict__ cw1,
              const float* __restrict__ cw3,
              const float* __restrict__ cw5,
              const float* __restrict__ Wk, const float* __restrict__ Wv,
              const float* __restrict__ Wr, const float* __restrict__ Wo,
              float* __restrict__ weff,
              unsigned short* __restrict__ W2k, unsigned short* __restrict__ W2v,
              unsigned short* __restrict__ W2r, unsigned short* __restrict__ Wo2) {
    int bid = blockIdx.x, c = threadIdx.x;
    if (bid < 25) {
        int k = bid;
        float a0 = alpha[0], a1 = alpha[1], a2 = alpha[2], a3 = alpha[3];
        float v = a3 * cw5[c * 25 + k];
        int ky = k / 5, kx = k % 5;
        if (ky >= 1 && ky <= 3 && kx >= 1 && kx <= 3)
            v += a2 * cw3[c * 9 + (ky - 1) * 3 + (kx - 1)];
        if (k == 12) v += a1 * cw1[c] + a0;
        weff[k * CC + c] = v;
    } else if (bid < 281) {
        int n = bid - 25;
        float a;
        unsigned short h;
        a = Wk[n * 256 + c]; h = f2bf(a); W2k[n * 512 + c] = h; W2k[n * 512 + 256 + c] = f2bf(a - bf2f(h));
        a = Wv[n * 256 + c]; h = f2bf(a); W2v[n * 512 + c] = h; W2v[n * 512 + 256 + c] = f2bf(a - bf2f(h));
        a = Wr[n * 256 + c]; h = f2bf(a); W2r[n * 512 + c] = h; W2r[n * 512 + 256 + c] = f2bf(a - bf2f(h));
    } else {
        int n = bid - 281;
        // Wo row n: [hi(512) | lo(512)]
        float a = Wo[n * 512 + c];
        unsigned short h = f2bf(a);
        Wo2[n * 1024 + c] = h;
        Wo2[n * 1024 + 512 + c] = f2bf(a - bf2f(h));
        float b = Wo[n * 512 + 256 + c];
        unsigned short h2 = f2bf(b);
        Wo2[n * 1024 + 256 + c] = h2;
        Wo2[n * 1024 + 512 + 256 + c] = f2bf(b - bf2f(h2));
    }
}

// ---------------------------------------------------------------------------
// Depthwise 5x5 conv, sliding-window over y. Output split [hi|lo] bf16 (512/row).
__global__ __launch_bounds__(256)
void omni_conv(const float* __restrict__ x,
               const float* __restrict__ weff,
               unsigned short* __restrict__ A2) {
    int xx = blockIdx.x;
    int y0 = blockIdx.y * 32;
    int b  = blockIdx.z;
    int c  = threadIdx.x;
    const float* xb = x + (size_t)b * TT * CC + c;
    unsigned short* Ab = A2 + (size_t)b * TT * 512 + c;

    float wk[25];
    #pragma unroll
    for (int k = 0; k < 25; ++k) wk[k] = weff[k * CC + c];

    float win[5][5];
    #pragma unroll
    for (int i = 0; i < 4; ++i) {
        int yy = y0 - 2 + i;
        #pragma unroll
        for (int dx = 0; dx < 5; ++dx) {
            int xc = xx + dx - 2;
            win[i][dx] = (yy >= 0 && xc >= 0 && xc < WW)
                         ? xb[(size_t)(yy * WW + xc) * CC] : 0.f;
        }
    }
    #pragma unroll
    for (int i = 0; i < 32; ++i) {
        int y = y0 + i;
        int yy = y + 2;
        #pragma unroll
        for (int dx = 0; dx < 5; ++dx) {
            int xc = xx + dx - 2;
            win[4][dx] = (yy < HH && xc >= 0 && xc < WW)
                         ? xb[(size_t)(yy * WW + xc) * CC] : 0.f;
        }
        float acc = 0.f;
        #pragma unroll
        for (int r = 0; r < 5; ++r)
            #pragma unroll
            for (int dx = 0; dx < 5; ++dx)
                acc = fmaf(wk[r * 5 + dx], win[r][dx], acc);
        unsigned short h = f2bf(acc);
        size_t o = (size_t)(y * WW + xx) * 512;
        Ab[o] = h;
        Ab[o + 256] = f2bf(acc - bf2f(h));
        #pragma unroll
        for (int r = 0; r < 4; ++r)
            #pragma unroll
            for (int dx = 0; dx < 5; ++dx)
                win[r][dx] = win[r + 1][dx];
    }
}

// ---------------------------------------------------------------------------
// MFMA GEMM (NT), chunked staging + T4 counted-vmcnt pipeline (r9-verified
// skeleton). KIND=0: kvr, bf16x3 (A[hi|lo]·W[hi|lo], 3 products, 4 tiles,
// 8 loads/stage, vmcnt(8)), C = bf16. KIND=1: out, A single bf16 (512/row),
// W [hi512|lo512] (2 products, 3 tiles, 6 loads/stage, vmcnt(6)), C = fp32.
template<int KIND>
__device__ __forceinline__ void mfma_core(const unsigned short* __restrict__ A0,
                                          const unsigned short* __restrict__ W2,
                                          void* __restrict__ Cv,
                                          int m_blk, int n_blk, bool act) {
    constexpr int NT = (KIND == 0) ? 4 : 3;   // tiles per chunk
    __shared__ __align__(16) unsigned short L[2][NT][128 * 32];
    int tid = threadIdx.x;
    int w = tid >> 6, l = tid & 63;
    int q = l >> 4, rr = l & 15;
    int wm = (w & 1) * 64, wn = (w >> 1) * 64;
    int srw = w * 16 + (l >> 2);
    int ss  = l & 3;

    const int NCHK = (KIND == 0) ? 8 : 16;
    const int LDA  = 512;
    const int LDW  = (KIND == 0) ? 512 : 1024;

    f32x4 acc[4][4];
    #pragma unroll
    for (int i = 0; i < 4; ++i)
        #pragma unroll
        for (int j = 0; j < 4; ++j)
            acc[i][j] = (f32x4){0.f, 0.f, 0.f, 0.f};

    auto stage = [&](int cc, int buf) {
        #pragma unroll
        for (int i = 0; i < 2; ++i) {
            int r = i * 64 + srw;
            int sl = (ss ^ ((r >> 1) & 3)) * 8;
            size_t arow = (size_t)(m_blk + r) * LDA;
            size_t wrow = (size_t)(n_blk + r) * LDW;
            int db = (i * 64 + w * 16) * 32;
            if (KIND == 0) {
                int ah = cc * 32, al = 256 + cc * 32;
                __builtin_amdgcn_global_load_lds(
                    (const __attribute__((address_space(1))) void*)(A0 + arow + ah + sl),
                    (__attribute__((address_space(3))) void*)&L[buf][0][db], 16, 0, 0);
                __builtin_amdgcn_global_load_lds(
                    (const __attribute__((address_space(1))) void*)(A0 + arow + al + sl),
                    (__attribute__((address_space(3))) void*)&L[buf][1][db], 16, 0, 0);
                __builtin_amdgcn_global_load_lds(
                    (const __attribute__((address_space(1))) void*)(W2 + wrow + cc * 32 + sl),
                    (__attribute__((address_space(3))) void*)&L[buf][2][db], 16, 0, 0);
                __builtin_amdgcn_global_load_lds(
                    (const __attribute__((address_space(1))) void*)(W2 + wrow + 256 + cc * 32 + sl),
                    (__attribute__((address_space(3))) void*)&L[buf][3][db], 16, 0, 0);
            } else {
                __builtin_amdgcn_global_load_lds(
                    (const __attribute__((address_space(1))) void*)(A0 + arow + cc * 32 + sl),
                    (__attribute__((address_space(3))) void*)&L[buf][0][db], 16, 0, 0);
                __builtin_amdgcn_global_load_lds(
                    (const __attribute__((address_space(1))) void*)(W2 + wrow + cc * 32 + sl),
                    (__attribute__((address_space(3))) void*)&L[buf][1][db], 16, 0, 0);
                __builtin_amdgcn_global_load_lds(
                    (const __attribute__((address_space(1))) void*)(W2 + wrow + 512 + cc * 32 + sl),
                    (__attribute__((address_space(3))) void*)&L[buf][2][db], 16, 0, 0);
            }
        }
    };

    stage(0, 0);
    stage(1, 1);

    for (int cc = 0; cc < NCHK; ++cc) {
        int buf = cc & 1;
        if (cc + 1 < NCHK) {
            if (KIND == 0) asm volatile("s_waitcnt vmcnt(8)" ::: "memory");
            else           asm volatile("s_waitcnt vmcnt(6)" ::: "memory");
        } else {
            asm volatile("s_waitcnt vmcnt(0)" ::: "memory");
        }
        __builtin_amdgcn_s_barrier();

        if (KIND == 0) {
            bf16x8 ah4[4], al4[4], wh4[4], wl4[4];
            #pragma unroll
            for (int f = 0; f < 4; ++f) {
                int Ra = wm + f * 16 + rr;
                int sa = (q ^ ((Ra >> 1) & 3)) * 8;
                ah4[f] = *(const bf16x8*)&L[buf][0][Ra * 32 + sa];
                al4[f] = *(const bf16x8*)&L[buf][1][Ra * 32 + sa];
                int Rw = wn + f * 16 + rr;
                int sw2 = (q ^ ((Rw >> 1) & 3)) * 8;
                wh4[f] = *(const bf16x8*)&L[buf][2][Rw * 32 + sw2];
                wl4[f] = *(const bf16x8*)&L[buf][3][Rw * 32 + sw2];
            }
            __builtin_amdgcn_s_setprio(1);
            #pragma unroll
            for (int fm = 0; fm < 4; ++fm)
                #pragma unroll
                for (int fn = 0; fn < 4; ++fn)
                    acc[fm][fn] = __builtin_amdgcn_mfma_f32_16x16x32_bf16(
                        ah4[fm], wh4[fn], acc[fm][fn], 0, 0, 0);
            #pragma unroll
            for (int fm = 0; fm < 4; ++fm)
                #pragma unroll
                for (int fn = 0; fn < 4; ++fn)
                    acc[fm][fn] = __builtin_amdgcn_mfma_f32_16x16x32_bf16(
                        al4[fm], wh4[fn], acc[fm][fn], 0, 0, 0);
            #pragma unroll
            for (int fm = 0; fm < 4; ++fm)
                #pragma unroll
                for (int fn = 0; fn < 4; ++fn)
                    acc[fm][fn] = __builtin_amdgcn_mfma_f32_16x16x32_bf16(
                        ah4[fm], wl4[fn], acc[fm][fn], 0, 0, 0);
            __builtin_amdgcn_s_setprio(0);
        } else {
            bf16x8 a4[4], wh4[4], wl4[4];
            #pragma unroll
            for (int f = 0; f < 4; ++f) {
                int Ra = wm + f * 16 + rr;
                int sa = (q ^ ((Ra >> 1) & 3)) * 8;
                a4[f] = *(const bf16x8*)&L[buf][0][Ra * 32 + sa];
                int Rw = wn + f * 16 + rr;
                int sw2 = (q ^ ((Rw >> 1) & 3)) * 8;
                wh4[f] = *(const bf16x8*)&L[buf][1][Rw * 32 + sw2];
                wl4[f] = *(const bf16x8*)&L[buf][2][Rw * 32 + sw2];
            }
            __builtin_amdgcn_s_setprio(1);
            #pragma unroll
            for (int fm = 0; fm < 4; ++fm)
                #pragma unroll
                for (int fn = 0; fn < 4; ++fn)
                    acc[fm][fn] = __builtin_amdgcn_mfma_f32_16x16x32_bf16(
                        a4[fm], wh4[fn], acc[fm][fn], 0, 0, 0);
            #pragma unroll
            for (int fm = 0; fm < 4; ++fm)
                #pragma unroll
                for (int fn = 0; fn < 4; ++fn)
                    acc[fm][fn] = __builtin_amdgcn_mfma_f32_16x16x32_bf16(
                        a4[fm], wl4[fn], acc[fm][fn], 0, 0, 0);
            __builtin_amdgcn_s_setprio(0);
        }

        __builtin_amdgcn_s_barrier();
        if (cc + 2 < NCHK) stage(cc + 2, buf);
    }

    // Epilogue: C/D layout col=lane&15, row=(lane>>4)*4+reg (m89-verified).
    #pragma unroll
    for (int fm = 0; fm < 4; ++fm)
        #pragma unroll
        for (int fn = 0; fn < 4; ++fn) {
            int col = n_blk + wn + fn * 16 + rr;
            int row0 = m_blk + wm + fm * 16 + q * 4;
            f32x4 v = acc[fm][fn];
            #pragma unroll
            for (int j = 0; j < 4; ++j) {
                float o = v[j];
                if (KIND == 0) {
                    if (act) o = 1.f / (1.f + __expf(-o));
                    ((unsigned short*)Cv)[(size_t)(row0 + j) * 256 + col] = f2bf(o);
                } else {
                    ((float*)Cv)[(size_t)(row0 + j) * 256 + col] = o;
                }
            }
        }
}

// XCD-bijective decode (unchanged).
__global__ __launch_bounds__(256, 2)
void gemm_kvr_mfma(const unsigned short* __restrict__ A2,
                   const unsigned short* __restrict__ W2k,
                   const unsigned short* __restrict__ W2v,
                   const unsigned short* __restrict__ W2r,
                   unsigned short* __restrict__ kb, unsigned short* __restrict__ vb,
                   unsigned short* __restrict__ rb) {
    int id = blockIdx.x;
    int xcd = id & 7;
    int j = id >> 3;
    int v = j % 6;
    int mq = j / 6;
    int m_blk = (mq * 8 + xcd) * 128;
    int mat = v >> 1;
    int n_blk = (v & 1) * 128;
    const unsigned short* W2 = (mat == 0) ? W2k : (mat == 1) ? W2v : W2r;
    unsigned short* C = (mat == 0) ? kb : (mat == 1) ? vb : rb;
    mfma_core<0>(A2, W2, C, m_blk, n_blk, mat == 2);
}

__global__ __launch_bounds__(256, 2)
void gemm_out_mfma(const unsigned short* __restrict__ xs_all,
                   const unsigned short* __restrict__ Wo2,
                   float* __restrict__ out) {
    int id = blockIdx.x;
    int xcd = id & 7;
    int j = id >> 3;
    int v = j & 1;
    int mq = j >> 1;
    int m_blk = (mq * 8 + xcd) * 128;
    mfma_core<1>(xs_all, Wo2, out, m_blk, v * 128, false);
}

// ---------------------------------------------------------------------------
// Chunk-parallel WKV; k/v/sr now bf16 (ushort). State fp32 in d_out scratch.
// Pass 1: local chunk states; 2 chunks (ch, ch+32) per thread for ILP.
__global__ __launch_bounds__(256)
void wkv_pass1(const unsigned short* __restrict__ kin,
               const unsigned short* __restrict__ vin,
               const float* __restrict__ sdecay,
               float* __restrict__ cs_a, float* __restrict__ cs_b,
               float* __restrict__ cs_p) {
    int chA = blockIdx.x, dir = blockIdx.y, bb = blockIdx.z, c = threadIdx.x;
    int chB = chA + NCH / 2;
    float wd = -expf(sdecay[dir * CC + c] * (1.f / TT));
    const unsigned short* kb = kin + (size_t)bb * TT * CC + c;
    const unsigned short* vb = vin + (size_t)bb * TT * CC + c;
    float aA = 0.f, bA = 0.f, pA = -1e38f;
    float aB = 0.f, bB = 0.f, pB = -1e38f;
    for (int i0 = 0; i0 < LCH; i0 += 8) {
        float kA8[8], vA8[8], kB8[8], vB8[8];
        #pragma unroll
        for (int i = 0; i < 8; ++i) {
            int ii = i0 + i;
            int sA = dir ? (ii * WW + chA) : (chA * LCH + ii);
            int sB = dir ? (ii * WW + chB) : (chB * LCH + ii);
            kA8[i] = bf2f(kb[(size_t)sA * CC]); vA8[i] = bf2f(vb[(size_t)sA * CC]);
            kB8[i] = bf2f(kb[(size_t)sB * CC]); vB8[i] = bf2f(vb[(size_t)sB * CC]);
        }
        #pragma unroll
        for (int i = 0; i < 8; ++i) {
            {
                float kt = kA8[i], vt = vA8[i];
                float ww2 = pA + wd;
                float p2 = fmaxf(ww2, kt);
                float f1 = __expf(ww2 - p2), f2 = __expf(kt - p2);
                aA = f1 * aA + f2 * vt; bA = f1 * bA + f2; pA = p2;
            }
            {
                float kt = kB8[i], vt = vB8[i];
                float ww2 = pB + wd;
                float p2 = fmaxf(ww2, kt);
                float f1 = __expf(ww2 - p2), f2 = __expf(kt - p2);
                aB = f1 * aB + f2 * vt; bB = f1 * bB + f2; pB = p2;
            }
        }
    }
    size_t base = (size_t)(bb * 2 + dir) * NCH * CC + c;
    size_t oA = base + (size_t)chA * CC, oB = base + (size_t)chB * CC;
    cs_a[oA] = aA; cs_b[oA] = bA; cs_p[oA] = pA;
    cs_a[oB] = aB; cs_b[oB] = bB; cs_p[oB] = pB;
}

// Pass 2 (r9-verified coalesced serial prefix): 16 blocks, L2-hot 3MB.
// Writes exclusive entry states in-place.
__global__ __launch_bounds__(256)
void wkv_pass2(const float* __restrict__ sdecay,
               float* __restrict__ cs_a, float* __restrict__ cs_b,
               float* __restrict__ cs_p) {
    int bb = blockIdx.x, dir = blockIdx.y, c = threadIdx.x;
    float wd = -expf(sdecay[dir * CC + c] * (1.f / TT));
    float Ld = (float)LCH * wd;
    float a = 0.f, b = 0.f, p = -1e38f;
    size_t base = (size_t)(bb * 2 + dir) * NCH * CC + c;
    for (int ch = 0; ch < NCH; ++ch) {
        size_t o = base + (size_t)ch * CC;
        float al = cs_a[o], bl = cs_b[o], pl = cs_p[o];
        cs_a[o] = a; cs_b[o] = b; cs_p[o] = p;
        float sh = p + Ld;
        float pn = fmaxf(sh, pl);
        float e1 = __expf(sh - pn), e2 = __expf(pl - pn);
        a = e1 * a + e2 * al; b = e1 * b + e2 * bl; p = pn;
    }
}

// Pass 3: entry state -> emit (out*sr) as single bf16 into xs_all[t][dir*256+c].
// 2 chunks per thread for ILP; v_rcp_f32 divide.
__global__ __launch_bounds__(256)
void wkv_pass3(const unsigned short* __restrict__ kin,
               const unsigned short* __restrict__ vin,
               const unsigned short* __restrict__ srin,
               const float* __restrict__ sdecay, const float* __restrict__ sfirst,
               const float* __restrict__ cs_a, const float* __restrict__ cs_b,
               const float* __restrict__ cs_p,
               unsigned short* __restrict__ xs_all) {
    int chA = blockIdx.x, dir = blockIdx.y, bb = blockIdx.z, c = threadIdx.x;
    int chB = chA + NCH / 2;
    int d = dir * CC + c;
    float u  = sfirst[d] * (1.f / TT);
    float wd = -expf(sdecay[d] * (1.f / TT));
    size_t base = (size_t)(bb * 2 + dir) * NCH * CC + c;
    size_t oA = base + (size_t)chA * CC, oB = base + (size_t)chB * CC;
    float aA = cs_a[oA], bA = cs_b[oA], pA = cs_p[oA];
    float aB = cs_a[oB], bB = cs_b[oB], pB = cs_p[oB];
    const unsigned short* kb  = kin  + (size_t)bb * TT * CC + c;
    const unsigned short* vb  = vin  + (size_t)bb * TT * CC + c;
    const unsigned short* srb = srin + (size_t)bb * TT * CC + c;
    unsigned short* xo = xs_all + (size_t)bb * TT * 512 + dir * 256 + c;
    for (int i0 = 0; i0 < LCH; i0 += 8) {
        float kA8[8], vA8[8], sA8[8], kB8[8], vB8[8], sB8[8];
        #pragma unroll
        for (int i = 0; i < 8; ++i) {
            int ii = i0 + i;
            int tA = chA * LCH + ii;
            int tB = chB * LCH + ii;
            int sA = dir ? (ii * WW + chA) : tA;
            int sB = dir ? (ii * WW + chB) : tB;
            kA8[i] = bf2f(kb[(size_t)sA * CC]); vA8[i] = bf2f(vb[(size_t)sA * CC]);
            sA8[i] = bf2f(srb[(size_t)tA * CC]);
            kB8[i] = bf2f(kb[(size_t)sB * CC]); vB8[i] = bf2f(vb[(size_t)sB * CC]);
            sB8[i] = bf2f(srb[(size_t)tB * CC]);
        }
        #pragma unroll
        for (int i = 0; i < 8; ++i) {
            {
                int t = chA * LCH + i0 + i;
                float kt = kA8[i], vt = vA8[i];
                float ww = u + kt;
                float qq = fmaxf(pA, ww);
                float e1 = __expf(pA - qq), e2 = __expf(ww - qq);
                float num = e1 * aA + e2 * vt;
                float den = e1 * bA + e2;
                float os = num * fast_rcp(den) * sA8[i];
                xo[(size_t)t * 512] = f2bf(os);
                float ww2 = pA + wd;
                float p2  = fmaxf(ww2, kt);
                float f1 = __expf(ww2 - p2), f2 = __expf(kt - p2);
                aA = f1 * aA + f2 * vt; bA = f1 * bA + f2; pA = p2;
            }
            {
                int t = chB * LCH + i0 + i;
                float kt = kB8[i], vt = vB8[i];
                float ww = u + kt;
                float qq = fmaxf(pB, ww);
                float e1 = __expf(pB - qq), e2 = __expf(ww - qq);
                float num = e1 * aB + e2 * vt;
                float den = e1 * bB + e2;
                float os = num * fast_rcp(den) * sB8[i];
                xo[(size_t)t * 512] = f2bf(os);
                float ww2 = pB + wd;
                float p2  = fmaxf(ww2, kt);
                float f1 = __expf(ww2 - p2), f2 = __expf(kt - p2);
                aB = f1 * aB + f2 * vt; bB = f1 * bB + f2; pB = p2;
            }
        }
    }
}

// ---------------------------------------------------------------------------
extern "C" void kernel_launch(void* const* d_in, const int* in_sizes, int n_in,
                              void* d_out, int out_size, void* d_ws, size_t ws_size,
                              hipStream_t stream) {
    const float* x     = (const float*)d_in[0];
    const float* alpha = (const float*)d_in[1];
    const float* cw1   = (const float*)d_in[2];
    const float* cw3   = (const float*)d_in[3];
    const float* cw5   = (const float*)d_in[4];
    const float* Wk    = (const float*)d_in[5];
    const float* Wv    = (const float*)d_in[6];
    const float* Wr    = (const float*)d_in[7];
    const float* Wo    = (const float*)d_in[8];
    const float* sd    = (const float*)d_in[9];
    const float* sf    = (const float*)d_in[10];
    (void)n_in; (void)out_size; (void)ws_size;

    int B = in_sizes[0] / (TT * CC);
    int M = B * TT;
    size_t S = (size_t)M * 1024;  // bytes per slot (M*512 ushorts)

    // ws: 3 slots (~100 MB).
    // slot0: A2 (conv out) -> later xs_all. slot1: kbuf | vbuf (bf16).
    // slot2: srbuf (bf16) | Wo2 (512 KB).
    char* wsb = (char*)d_ws;
    unsigned short* A2     = (unsigned short*)wsb;
    unsigned short* xs_all = A2;
    unsigned short* kbuf   = (unsigned short*)(wsb + 1 * S);
    unsigned short* vbuf   = (unsigned short*)(wsb + 1 * S + S / 2);
    unsigned short* srbuf  = (unsigned short*)(wsb + 2 * S);
    unsigned short* Wo2    = (unsigned short*)(wsb + 2 * S + S / 2);

    // d_out as scratch until gemm_out overwrites it entirely.
    size_t SC = (size_t)B * 2 * NCH * CC;
    char* ob = (char*)d_out;
    float* cs_a = (float*)ob;
    float* cs_b = (float*)(ob + SC * 4);
    float* cs_p = (float*)(ob + 2 * SC * 4);
    float* weff = (float*)(ob + 3 * SC * 4);
    unsigned short* W2k = (unsigned short*)(ob + (4u << 20));
    unsigned short* W2v = (unsigned short*)(ob + (4u << 20) + 262144);
    unsigned short* W2r = (unsigned short*)(ob + (4u << 20) + 524288);

    prep_all<<<537, CC, 0, stream>>>(alpha, cw1, cw3, cw5, Wk, Wv, Wr, Wo,
                                     weff, W2k, W2v, W2r, Wo2);
    omni_conv<<<dim3(WW, 2, B), CC, 0, stream>>>(x, weff, A2);

    gemm_kvr_mfma<<<(M / 128) * 6, 256, 0, stream>>>(A2, W2k, W2v, W2r,
                                                     kbuf, vbuf, srbuf);

    wkv_pass1<<<dim3(NCH / 2, 2, B), 256, 0, stream>>>(kbuf, vbuf, sd,
                                                       cs_a, cs_b, cs_p);
    wkv_pass2<<<dim3(B, 2), 256, 0, stream>>>(sd, cs_a, cs_b, cs_p);
    wkv_pass3<<<dim3(NCH / 2, 2, B), 256, 0, stream>>>(kbuf, vbuf, srbuf, sd, sf,
                                                       cs_a, cs_b, cs_p, xs_all);

    gemm_out_mfma<<<(M / 128) * 2, 256, 0, stream>>>(xs_all, Wo2, (float*)d_out);
}